// Round 7
// baseline (812.455 us; speedup 1.0000x reference)
//
#include <hip/hip_runtime.h>
#include <hip/hip_bf16.h>

typedef unsigned short u16;
typedef short bf16x8 __attribute__((ext_vector_type(8)));
typedef float f32x4 __attribute__((ext_vector_type(4)));

__device__ __forceinline__ float b2f(u16 u) {
  union { float f; unsigned int i; } v; v.i = ((unsigned int)u) << 16; return v.f;
}
__device__ __forceinline__ u16 f2b(float f) {
  union { float f; unsigned int i; } v; v.f = f;
  unsigned int r = v.i + 0x7fffu + ((v.i >> 16) & 1u);
  return (u16)(r >> 16);
}
__device__ __forceinline__ u16 to_b(float v) { return f2b(v); }
__device__ __forceinline__ u16 to_b(u16 v) { return v; }
__device__ __forceinline__ float to_f(float v) { return v; }
__device__ __forceinline__ float to_f(u16 v) { return b2f(v); }

// async 16B global -> LDS (dest = uniform lds base + lane*16)
__device__ __forceinline__ void gl_lds16(const u16* g, u16* l) {
  __builtin_amdgcn_global_load_lds(
      (const __attribute__((address_space(1))) unsigned int*)g,
      (__attribute__((address_space(3))) unsigned int*)l, 16, 0, 0);
}

// ---------------- generic NT GEMM (verified) ----------------
// Split-partial trick: with nsplit=1, sA/sB act as per-z K-offsets and sC as
// per-z C-offset -> one launch writes independent bf16 partials per z.
template <bool RELU, bool ATOMIC>
__global__ __launch_bounds__(256)
void gemm_nt(const u16* __restrict__ A, const u16* __restrict__ Bt,
             const float* __restrict__ bias, void* __restrict__ Cv,
             int N, int K, int nsplit, int lda, int ldb, int ldc,
             long sA, long sB, long sC, float scale) {
  __shared__ __align__(16) u16 As[128 * 64];
  __shared__ __align__(16) u16 Bs[128 * 64];
  const int z = blockIdx.z;
  const int batch = z / nsplit, split = z - batch * nsplit;
  const int Ks = K / nsplit;
  const u16* Ab = A + (long)batch * sA + (long)split * Ks;
  const u16* Bb = Bt + (long)batch * sB + (long)split * Ks;
  const int m0 = blockIdx.y * 128, n0 = blockIdx.x * 128;
  const int t = threadIdx.x, w = t >> 6, lane = t & 63;
  const int wm = (w >> 1) * 64, wn = (w & 1) * 64;
  const int lr = lane & 15, q = lane >> 4;

  int srow[4], scol[4];
#pragma unroll
  for (int i = 0; i < 4; i++) {
    int n = w * 256 + i * 64 + lane;
    srow[i] = n >> 3;
    scol[i] = (((n & 7) ^ ((n >> 3) & 7)) * 8);
  }

  f32x4 acc[4][4];
#pragma unroll
  for (int i = 0; i < 4; i++)
#pragma unroll
    for (int j = 0; j < 4; j++) acc[i][j] = (f32x4){0.f, 0.f, 0.f, 0.f};

  for (int k0 = 0; k0 < Ks; k0 += 64) {
#pragma unroll
    for (int i = 0; i < 4; i++)
      gl_lds16(Ab + (long)(m0 + srow[i]) * lda + k0 + scol[i], &As[(w * 256 + i * 64) * 8]);
#pragma unroll
    for (int i = 0; i < 4; i++)
      gl_lds16(Bb + (long)(n0 + srow[i]) * ldb + k0 + scol[i], &Bs[(w * 256 + i * 64) * 8]);
    __syncthreads();
#pragma unroll
    for (int kk = 0; kk < 2; kk++) {
      bf16x8 af[4], bfr[4];
#pragma unroll
      for (int i = 0; i < 4; i++) {
        int row = wm + i * 16 + lr;
        af[i] = *(const bf16x8*)&As[row * 64 + (((kk * 4 + q) ^ (row & 7)) * 8)];
      }
#pragma unroll
      for (int j = 0; j < 4; j++) {
        int row = wn + j * 16 + lr;
        bfr[j] = *(const bf16x8*)&Bs[row * 64 + (((kk * 4 + q) ^ (row & 7)) * 8)];
      }
#pragma unroll
      for (int i = 0; i < 4; i++)
#pragma unroll
        for (int j = 0; j < 4; j++)
          acc[i][j] = __builtin_amdgcn_mfma_f32_16x16x32_bf16(af[i], bfr[j], acc[i][j], 0, 0, 0);
    }
    __syncthreads();
  }

#pragma unroll
  for (int j = 0; j < 4; j++) {
    int cg = n0 + wn + j * 16 + lr;
    float bb = (!ATOMIC && bias) ? bias[cg] : 0.0f;
#pragma unroll
    for (int i = 0; i < 4; i++) {
      int rbase = m0 + wm + i * 16 + q * 4;
#pragma unroll
      for (int r = 0; r < 4; r++) {
        float vv = acc[i][j][r] * scale;
        if (ATOMIC) {
          atomicAdd((float*)Cv + (long)batch * sC + (long)(rbase + r) * ldc + cg, vv);
        } else {
          vv += bb;
          if (RELU) vv = fmaxf(vv, 0.0f);
          ((u16*)Cv)[(long)batch * sC + (long)(rbase + r) * ldc + cg] = f2b(vv);
        }
      }
    }
  }
}

// ---------------- fused flash attention v3 ----------------
// Block: 64 Q-rows (4 waves x 16), one KV QUARTER (1024) in 128-tiles.
// Grid 64x4x4 = 1024 blocks = 4 blocks/CU (16 waves/CU). Single 32 KB LDS
// buffer shared by K-chunks, P-transpose, V-chunks. Static softmax (scores
// bounded; validated). Emits bf16 partial O + fp32 partial row-sums per quarter.
__global__ __launch_bounds__(256, 4)
void flash_attn(const u16* __restrict__ QKV, const u16* __restrict__ Vt,
                u16* __restrict__ attp, float* __restrict__ lbp, float scl) {
  __shared__ __align__(16) u16 buf[128 * 128];  // 32 KB shared stage (K / P / V)
  const int qt = blockIdx.x;      // 64 Q-tiles
  const int quar = blockIdx.y;    // 4 KV quarters
  const int batch = blockIdx.z;   // 4 batches
  const int t = threadIdx.x, w = t >> 6, lane = t & 63;
  const int lr = lane & 15, q = lane >> 4;
  const long rowbase = (long)batch * 4096 + qt * 64;
  const u16* Qrow  = QKV + (rowbase + w * 16 + lr) * 1536;                   // Q cols [0,512)
  const u16* Kbase = QKV + ((long)batch * 4096 + quar * 1024) * 1536 + 512;  // K cols [512,1024)
  const u16* Vtb   = Vt + (long)batch * 512 * 4096 + quar * 1024;            // [512,4096] ld 4096
  u16* Pw = buf + w * (16 * 136);  // P aliases buf; stride 136 (16B-aligned rows)

  f32x4 O[32];  // O[dc*8+j]: row=q*4+r, col=dc*128 + j*16 + lr
#pragma unroll
  for (int i = 0; i < 32; i++) O[i] = (f32x4){0.f, 0.f, 0.f, 0.f};
  float lsum[4] = {0.f, 0.f, 0.f, 0.f};

  for (int kv = 0; kv < 8; kv++) {
    f32x4 S[8];
#pragma unroll
    for (int j = 0; j < 8; j++) S[j] = (f32x4){0.f, 0.f, 0.f, 0.f};

    // ---- QK^T: 4 K-chunks of [128 kv x 128 k] = 32 KB each ----
    for (int kc = 0; kc < 4; kc++) {
#pragma unroll
      for (int rr = 0; rr < 8; rr++) {
        int n = rr * 256 + t;
        int row = n >> 4, c = (n & 15) ^ (row & 15);
        gl_lds16(Kbase + (long)(kv * 128 + row) * 1536 + kc * 128 + c * 8,
                 &buf[(rr * 256 + w * 64) * 8]);
      }
      bf16x8 Qf[4];
#pragma unroll
      for (int ss = 0; ss < 4; ss++)
        Qf[ss] = *(const bf16x8*)(Qrow + kc * 128 + ss * 32 + q * 8);
      __syncthreads();
#pragma unroll
      for (int ss = 0; ss < 4; ss++)
#pragma unroll
        for (int j = 0; j < 8; j++) {
          int row = j * 16 + lr;
          bf16x8 Kf = *(const bf16x8*)&buf[row * 128 + (((ss * 4 + q) ^ lr) * 8)];
          S[j] = __builtin_amdgcn_mfma_f32_16x16x32_bf16(Qf[ss], Kf, S[j], 0, 0, 0);
        }
      __syncthreads();  // buf free for next stage
    }

    // ---- static softmax: P = exp(S*scl); transpose via wave-private buf slice ----
    float psum[4] = {0.f, 0.f, 0.f, 0.f};
#pragma unroll
    for (int j = 0; j < 8; j++)
#pragma unroll
      for (int r = 0; r < 4; r++) {
        float e = __expf(S[j][r] * scl);
        psum[r] += e;
        Pw[(q * 4 + r) * 136 + j * 16 + lr] = f2b(e);
      }
#pragma unroll
    for (int r = 0; r < 4; r++) {
#pragma unroll
      for (int o = 1; o < 16; o <<= 1) psum[r] += __shfl_xor(psum[r], o);
      lsum[r] += psum[r];
    }
    bf16x8 Pf[4];  // A-frag: row=lr, k=t4*32+q*8 (same-wave read, lgkm-ordered)
#pragma unroll
    for (int t4 = 0; t4 < 4; t4++)
      Pf[t4] = *(const bf16x8*)&Pw[lr * 136 + t4 * 32 + q * 8];
    __syncthreads();  // all P reads done before V overwrites buf

    // ---- PV: 4 V-chunks of [128 d x 128 kv] = 32 KB each ----
    for (int dc = 0; dc < 4; dc++) {
#pragma unroll
      for (int rr = 0; rr < 8; rr++) {
        int n = rr * 256 + t;
        int row = n >> 4, c = (n & 15) ^ (row & 15);
        gl_lds16(Vtb + (long)(dc * 128 + row) * 4096 + kv * 128 + c * 8,
                 &buf[(rr * 256 + w * 64) * 8]);
      }
      __syncthreads();
#pragma unroll
      for (int t4 = 0; t4 < 4; t4++)
#pragma unroll
        for (int j = 0; j < 8; j++) {
          int row = j * 16 + lr;
          bf16x8 Vf = *(const bf16x8*)&buf[row * 128 + (((t4 * 4 + q) ^ lr) * 8)];
          O[dc * 8 + j] = __builtin_amdgcn_mfma_f32_16x16x32_bf16(Pf[t4], Vf, O[dc * 8 + j], 0, 0, 0);
        }
      __syncthreads();
    }
  }

  // ---- epilogue: bf16 partial-O stores (no atomics) ----
  u16* op = attp + (long)quar * 16384 * 512;
#pragma unroll
  for (int i = 0; i < 32; i++) {
    int col = (i >> 3) * 128 + (i & 7) * 16 + lr;
#pragma unroll
    for (int r = 0; r < 4; r++)
      op[(rowbase + w * 16 + q * 4 + r) * 512 + col] = f2b(O[i][r]);
  }
  if (lr == 0)
#pragma unroll
    for (int r = 0; r < 4; r++)
      lbp[(long)quar * 16384 + rowbase + w * 16 + q * 4 + r] = lsum[r];
}

// ---------------- support kernels ----------------
template <typename TS>
__global__ __launch_bounds__(1024)
void transpose_b(const TS* __restrict__ src, u16* __restrict__ dst,
                 int R, int Cc, int src_ld, long sbs, long dbs) {
  __shared__ u16 tile[32][33];
  int r = blockIdx.y * 32 + threadIdx.y;
  int c = blockIdx.x * 32 + threadIdx.x;
  tile[threadIdx.y][threadIdx.x] = to_b(src[(long)blockIdx.z * sbs + (long)r * src_ld + c]);
  __syncthreads();
  int rr = blockIdx.x * 32 + threadIdx.y;
  int cc = blockIdx.y * 32 + threadIdx.x;
  dst[(long)blockIdx.z * dbs + (long)rr * R + cc] = tile[threadIdx.x][threadIdx.y];
}

__global__ __launch_bounds__(256)
void f32_to_bf16(const float* __restrict__ s, u16* __restrict__ d) {
  long i = ((long)blockIdx.x * 256 + threadIdx.x) * 8;
  float4 a0 = *(const float4*)(s + i);
  float4 a1 = *(const float4*)(s + i + 4);
  u16 tmp[8] = {f2b(a0.x), f2b(a0.y), f2b(a0.z), f2b(a0.w),
                f2b(a1.x), f2b(a1.y), f2b(a1.z), f2b(a1.w)};
  *(uint4*)(d + i) = *(uint4*)tmp;
}

// x1 = LN(x + (p0+p1+p2+p3)/l; g,b) -> bf16. Row 512, 1 row/wave.
__global__ __launch_bounds__(256)
void add_ln_att(const float* __restrict__ X, const u16* __restrict__ attp,
                const float* __restrict__ lbp,
                const float* __restrict__ g, const float* __restrict__ b,
                u16* __restrict__ O) {
  const int row = blockIdx.x * 4 + (threadIdx.x >> 6);
  const int lane = threadIdx.x & 63;
  const size_t base = (size_t)row * 512 + lane * 8;
  const float inv = 1.0f / (lbp[row] + lbp[16384 + row] + lbp[32768 + row] + lbp[49152 + row]);
  float acc[8] = {0, 0, 0, 0, 0, 0, 0, 0};
#pragma unroll
  for (int p = 0; p < 4; p++) {
    uint4 pv = *(const uint4*)(attp + (long)p * 16384 * 512 + base);
    const u16* s = (const u16*)&pv;
#pragma unroll
    for (int i = 0; i < 8; i++) acc[i] += b2f(s[i]);
  }
  float z[8];
  float s1a = 0.f, s2a = 0.f;
#pragma unroll
  for (int i = 0; i < 8; i++) {
    z[i] = X[base + i] + acc[i] * inv;
    s1a += z[i]; s2a += z[i] * z[i];
  }
#pragma unroll
  for (int o = 32; o > 0; o >>= 1) { s1a += __shfl_xor(s1a, o); s2a += __shfl_xor(s2a, o); }
  const float mu = s1a * (1.0f / 512.0f);
  const float var = s2a * (1.0f / 512.0f) - mu * mu;
  const float rstd = rsqrtf(var + 1e-5f);
#pragma unroll
  for (int i = 0; i < 8; i++) {
    int c = lane * 8 + i;
    O[base + i] = f2b((z[i] - mu) * rstd * g[c] + b[c]);
  }
}

// out = LN(x1 + p0 + p1 + eb; g,b) -> fp32. Row 512, 1 row/wave.
__global__ __launch_bounds__(256)
void add_ln_ffn(const u16* __restrict__ X, const u16* __restrict__ P0,
                const u16* __restrict__ P1, const float* __restrict__ eb,
                const float* __restrict__ g, const float* __restrict__ b,
                float* __restrict__ O) {
  const int row = blockIdx.x * 4 + (threadIdx.x >> 6);
  const int lane = threadIdx.x & 63;
  const size_t base = (size_t)row * 512 + lane * 8;
  uint4 xv = *(const uint4*)(X + base);
  uint4 a0 = *(const uint4*)(P0 + base);
  uint4 a1 = *(const uint4*)(P1 + base);
  const u16* xs = (const u16*)&xv;
  const u16* s0 = (const u16*)&a0;
  const u16* s1 = (const u16*)&a1;
  float z[8];
  float s1a = 0.f, s2a = 0.f;
#pragma unroll
  for (int i = 0; i < 8; i++) {
    int c = lane * 8 + i;
    z[i] = b2f(xs[i]) + b2f(s0[i]) + b2f(s1[i]) + eb[c];
    s1a += z[i]; s2a += z[i] * z[i];
  }
#pragma unroll
  for (int o = 32; o > 0; o >>= 1) { s1a += __shfl_xor(s1a, o); s2a += __shfl_xor(s2a, o); }
  const float mu = s1a * (1.0f / 512.0f);
  const float var = s2a * (1.0f / 512.0f) - mu * mu;
  const float rstd = rsqrtf(var + 1e-5f);
#pragma unroll
  for (int i = 0; i < 8; i++) {
    int c = lane * 8 + i;
    O[base + i] = (z[i] - mu) * rstd * g[c] + b[c];
  }
}

__global__ __launch_bounds__(256)
void concat3(const float* __restrict__ a, const float* __restrict__ b,
             const float* __restrict__ c, float* __restrict__ o) {
  int i = threadIdx.x + blockIdx.x * 256;
  if (i < 512) o[i] = a[i];
  else if (i < 1024) o[i] = b[i - 512];
  else if (i < 1536) o[i] = c[i - 1024];
}

extern "C" void kernel_launch(void* const* d_in, const int* in_sizes, int n_in,
                              void* d_out, int out_size, void* d_ws, size_t ws_size,
                              hipStream_t stream) {
  const float* x   = (const float*)d_in[0];
  const float* Wq  = (const float*)d_in[1];
  const float* bq  = (const float*)d_in[2];
  const float* Wk  = (const float*)d_in[3];
  const float* bk  = (const float*)d_in[4];
  const float* Wv  = (const float*)d_in[5];
  const float* bv  = (const float*)d_in[6];
  const float* g1  = (const float*)d_in[7];
  const float* b1  = (const float*)d_in[8];
  const float* g2  = (const float*)d_in[9];
  const float* b2  = (const float*)d_in[10];
  const float* W1  = (const float*)d_in[11];
  const float* bf1 = (const float*)d_in[12];
  const float* W2  = (const float*)d_in[13];
  const float* bf2 = (const float*)d_in[14];
  float* out = (float*)d_out;

  char* ws = (char*)d_ws;
  const size_t MB = 1048576;
  u16*   QKV   = (u16*)(ws + 0);          // [16384,1536] bf16, 48 MB
  u16*   Vt    = (u16*)(ws + 48 * MB);    // [4,512,4096] bf16, 16 MB
  u16*   attp  = (u16*)(ws + 64 * MB);    // [4][16384,512] bf16 partials, 64 MB
  u16*   h     = (u16*)(ws + 64 * MB);    // [16384,2048] bf16 (after attp dead)
  float* lbp   = (float*)(ws + 128 * MB); // [4][16384] fp32 partial row sums
  u16*   x1    = (u16*)(ws + 129 * MB);   // [16384,512] bf16, 16 MB
  u16*   ffnp  = (u16*)(ws + 145 * MB);   // [2][16384,512] bf16 partials, 32 MB
  u16*   xb    = (u16*)(ws + 145 * MB);   // bf16(x), 16 MB — dead before ffnp written
  u16*   wqkvt = (u16*)(ws + 177 * MB);   // [1536,512] bf16
  u16*   w1t   = wqkvt + 1536 * 512;      // [2048,512] bf16
  u16*   w2t   = w1t + 2048 * 512;        // [512,2048] bf16
  float* bqkv  = (float*)(w2t + 512 * 2048); // [1536] fp32

  dim3 tb(32, 32);
  f32_to_bf16<<<4096, 256, 0, stream>>>(x, xb);
  transpose_b<float><<<dim3(16, 16, 1), tb, 0, stream>>>(Wq, wqkvt,              512, 512, 512, 0, 0);
  transpose_b<float><<<dim3(16, 16, 1), tb, 0, stream>>>(Wk, wqkvt + 512 * 512,  512, 512, 512, 0, 0);
  transpose_b<float><<<dim3(16, 16, 1), tb, 0, stream>>>(Wv, wqkvt + 1024 * 512, 512, 512, 512, 0, 0);
  transpose_b<float><<<dim3(64, 16, 1), tb, 0, stream>>>(W1, w1t, 512, 2048, 2048, 0, 0);
  transpose_b<float><<<dim3(16, 64, 1), tb, 0, stream>>>(W2, w2t, 2048, 512, 512, 0, 0);
  concat3<<<6, 256, 0, stream>>>(bq, bk, bv, bqkv);

  // Fused QKV projection
  gemm_nt<false, false><<<dim3(12, 128, 1), 256, 0, stream>>>(
      xb, wqkvt, bqkv, QKV, 1536, 512, 1, 512, 512, 1536, 0, 0, 0, 1.0f);

  // V^T per batch
  transpose_b<u16><<<dim3(16, 128, 4), tb, 0, stream>>>(
      QKV + 1024, Vt, 4096, 512, 1536, 4096L * 1536, 512L * 4096);

  const float scl = 0.044194173824159216f;  // 1/sqrt(512)
  // Fused attention: 4 KV quarters -> 1024 blocks (4/CU), bf16 partials
  flash_attn<<<dim3(64, 4, 4), 256, 0, stream>>>(QKV, Vt, attp, lbp, scl);

  // x1 = LN(x + sum(partials)/l)
  add_ln_att<<<4096, 256, 0, stream>>>(x, attp, lbp, g1, b1, x1);
  // h = relu(x1 W1 + bf1)   (h overwrites dead attp region)
  gemm_nt<true, false><<<dim3(16, 128, 1), 256, 0, stream>>>(
      x1, w1t, bf1, h, 2048, 512, 1, 512, 512, 2048, 0, 0, 0, 1.0f);
  // ffnp[z] = h[:, z*1024:(z+1)*1024] W2[z*1024:(z+1)*1024, :] (bf16 partials, no atomics)
  gemm_nt<false, false><<<dim3(4, 128, 2), 256, 0, stream>>>(
      h, w2t, nullptr, ffnp, 512, 1024, 1, 2048, 2048, 512,
      1024, 1024, 16384L * 512, 1.0f);
  // out = LN(x1 + p0 + p1 + bf2) -> fp32
  add_ln_ffn<<<4096, 256, 0, stream>>>(
      x1, ffnp, ffnp + 16384L * 512, bf2, g2, b2, out);
}

// Round 9
// 598.750 us; speedup vs baseline: 1.3569x; 1.3569x over previous
//
#include <hip/hip_runtime.h>
#include <hip/hip_bf16.h>

typedef unsigned short u16;
typedef short bf16x8 __attribute__((ext_vector_type(8)));
typedef float f32x4 __attribute__((ext_vector_type(4)));

__device__ __forceinline__ float b2f(u16 u) {
  union { float f; unsigned int i; } v; v.i = ((unsigned int)u) << 16; return v.f;
}
__device__ __forceinline__ u16 f2b(float f) {
  union { float f; unsigned int i; } v; v.f = f;
  unsigned int r = v.i + 0x7fffu + ((v.i >> 16) & 1u);
  return (u16)(r >> 16);
}
__device__ __forceinline__ u16 to_b(float v) { return f2b(v); }
__device__ __forceinline__ u16 to_b(u16 v) { return v; }
__device__ __forceinline__ float to_f(float v) { return v; }
__device__ __forceinline__ float to_f(u16 v) { return b2f(v); }

// async 16B global -> LDS (dest = uniform lds base + lane*16)
__device__ __forceinline__ void gl_lds16(const u16* g, u16* l) {
  __builtin_amdgcn_global_load_lds(
      (const __attribute__((address_space(1))) unsigned int*)g,
      (__attribute__((address_space(3))) unsigned int*)l, 16, 0, 0);
}

// ---------------- generic NT GEMM (verified) ----------------
template <bool RELU, bool ATOMIC>
__global__ __launch_bounds__(256)
void gemm_nt(const u16* __restrict__ A, const u16* __restrict__ Bt,
             const float* __restrict__ bias, void* __restrict__ Cv,
             int N, int K, int nsplit, int lda, int ldb, int ldc,
             long sA, long sB, long sC, float scale) {
  __shared__ __align__(16) u16 As[128 * 64];
  __shared__ __align__(16) u16 Bs[128 * 64];
  const int z = blockIdx.z;
  const int batch = z / nsplit, split = z - batch * nsplit;
  const int Ks = K / nsplit;
  const u16* Ab = A + (long)batch * sA + (long)split * Ks;
  const u16* Bb = Bt + (long)batch * sB + (long)split * Ks;
  const int m0 = blockIdx.y * 128, n0 = blockIdx.x * 128;
  const int t = threadIdx.x, w = t >> 6, lane = t & 63;
  const int wm = (w >> 1) * 64, wn = (w & 1) * 64;
  const int lr = lane & 15, q = lane >> 4;

  int srow[4], scol[4];
#pragma unroll
  for (int i = 0; i < 4; i++) {
    int n = w * 256 + i * 64 + lane;
    srow[i] = n >> 3;
    scol[i] = (((n & 7) ^ ((n >> 3) & 7)) * 8);
  }

  f32x4 acc[4][4];
#pragma unroll
  for (int i = 0; i < 4; i++)
#pragma unroll
    for (int j = 0; j < 4; j++) acc[i][j] = (f32x4){0.f, 0.f, 0.f, 0.f};

  for (int k0 = 0; k0 < Ks; k0 += 64) {
#pragma unroll
    for (int i = 0; i < 4; i++)
      gl_lds16(Ab + (long)(m0 + srow[i]) * lda + k0 + scol[i], &As[(w * 256 + i * 64) * 8]);
#pragma unroll
    for (int i = 0; i < 4; i++)
      gl_lds16(Bb + (long)(n0 + srow[i]) * ldb + k0 + scol[i], &Bs[(w * 256 + i * 64) * 8]);
    __syncthreads();
#pragma unroll
    for (int kk = 0; kk < 2; kk++) {
      bf16x8 af[4], bfr[4];
#pragma unroll
      for (int i = 0; i < 4; i++) {
        int row = wm + i * 16 + lr;
        af[i] = *(const bf16x8*)&As[row * 64 + (((kk * 4 + q) ^ (row & 7)) * 8)];
      }
#pragma unroll
      for (int j = 0; j < 4; j++) {
        int row = wn + j * 16 + lr;
        bfr[j] = *(const bf16x8*)&Bs[row * 64 + (((kk * 4 + q) ^ (row & 7)) * 8)];
      }
#pragma unroll
      for (int i = 0; i < 4; i++)
#pragma unroll
        for (int j = 0; j < 4; j++)
          acc[i][j] = __builtin_amdgcn_mfma_f32_16x16x32_bf16(af[i], bfr[j], acc[i][j], 0, 0, 0);
    }
    __syncthreads();
  }

#pragma unroll
  for (int j = 0; j < 4; j++) {
    int cg = n0 + wn + j * 16 + lr;
    float bb = (!ATOMIC && bias) ? bias[cg] : 0.0f;
#pragma unroll
    for (int i = 0; i < 4; i++) {
      int rbase = m0 + wm + i * 16 + q * 4;
#pragma unroll
      for (int r = 0; r < 4; r++) {
        float vv = acc[i][j][r] * scale;
        if (ATOMIC) {
          atomicAdd((float*)Cv + (long)batch * sC + (long)(rbase + r) * ldc + cg, vv);
        } else {
          vv += bb;
          if (RELU) vv = fmaxf(vv, 0.0f);
          ((u16*)Cv)[(long)batch * sC + (long)(rbase + r) * ldc + cg] = f2b(vv);
        }
      }
    }
  }
}

// ---------------- fused flash attention v4b: double-buffered, static LDS ----------------
// Block: 64 Q-rows (4 waves x 16), one KV HALF (2048) in 128-tiles. Grid 64x2x4.
// B2[2] ping-pong (provenance-visible indexing -> ds_read, no generic pointers).
// One barrier per chunk: prefetch chunk g+1 into B2[par^1] while computing g from
// B2[par]; barrier drains the DMA after a full compute phase. P transposes into
// the free buffer (reads complete before next DMA overwrites it).
#define STAGE_K(kvv, kcc, sel)                                               \
  {                                                                          \
    _Pragma("unroll") for (int rr = 0; rr < 8; rr++)                         \
        gl_lds16(Kbase + (long)((kvv) * 128 + srow[rr]) * 1536 +             \
                     (kcc) * 128 + scol8[rr],                                \
                 &B2[(sel)][ldsd[rr]]);                                      \
  }
#define STAGE_V(kvv, dcc, sel)                                               \
  {                                                                          \
    _Pragma("unroll") for (int rr = 0; rr < 8; rr++)                         \
        gl_lds16(Vtb + (long)((dcc) * 128 + srow[rr]) * 4096 +               \
                     (kvv) * 128 + scol8[rr],                                \
                 &B2[(sel)][ldsd[rr]]);                                      \
  }

__global__ __launch_bounds__(256, 2)
void flash_attn(const u16* __restrict__ QKV, const u16* __restrict__ Vt,
                u16* __restrict__ attp, float* __restrict__ lbp, float scl) {
  __shared__ __align__(16) u16 B2[2][128 * 128];  // 2 x 32 KB
  const int qt = blockIdx.x, half = blockIdx.y, batch = blockIdx.z;
  const int t = threadIdx.x, w = t >> 6, lane = t & 63;
  const int lr = lane & 15, q = lane >> 4;
  const long rowbase = (long)batch * 4096 + qt * 64;
  const u16* Qrow  = QKV + (rowbase + w * 16 + lr) * 1536;                  // Q cols [0,512)
  const u16* Kbase = QKV + ((long)batch * 4096 + half * 2048) * 1536 + 512; // K cols [512,1024)
  const u16* Vtb   = Vt + (long)batch * 512 * 4096 + half * 2048;           // [512,4096] ld 4096

  int srow[8], scol8[8], ldsd[8];
#pragma unroll
  for (int rr = 0; rr < 8; rr++) {
    int n = rr * 256 + t;
    srow[rr] = n >> 4;
    scol8[rr] = ((n & 15) ^ ((n >> 4) & 15)) * 8;
    ldsd[rr] = (rr * 256 + w * 64) * 8;  // wave-uniform base; DMA adds lane*16B
  }

  f32x4 O[32];  // O[dc*8+j]: row=q*4+r, col=dc*128 + j*16 + lr
#pragma unroll
  for (int i = 0; i < 32; i++) O[i] = (f32x4){0.f, 0.f, 0.f, 0.f};
  float lsum[4] = {0.f, 0.f, 0.f, 0.f};

  STAGE_K(0, 0, 0);  // prologue
  __syncthreads();
  int par = 0;

  for (int kv = 0; kv < 16; kv++) {
    f32x4 S[8];
#pragma unroll
    for (int j = 0; j < 8; j++) S[j] = (f32x4){0.f, 0.f, 0.f, 0.f};

    // ---- QK^T: 4 chunks [128 kv x 128 k]; prefetch next while computing ----
    for (int kc = 0; kc < 4; kc++) {
      if (kc < 3) { STAGE_K(kv, kc + 1, par ^ 1); }
      else        { STAGE_V(kv, 0, par ^ 1); }
      bf16x8 Qf[4];
#pragma unroll
      for (int ss = 0; ss < 4; ss++)
        Qf[ss] = *(const bf16x8*)(Qrow + kc * 128 + ss * 32 + q * 8);
#pragma unroll
      for (int ss = 0; ss < 4; ss++)
#pragma unroll
        for (int j = 0; j < 8; j++) {
          int row = j * 16 + lr;
          bf16x8 Kf = *(const bf16x8*)&B2[par][row * 128 + (((ss * 4 + q) ^ lr) * 8)];
          S[j] = __builtin_amdgcn_mfma_f32_16x16x32_bf16(Qf[ss], Kf, S[j], 0, 0, 0);
        }
      __syncthreads();  // drains prefetch DMA + protects current buffer reuse
      par ^= 1;
    }

    // ---- P interlude: V0 resident in B2[par]; B2[par^1] free (K3 reads done) ----
    float psum[4] = {0.f, 0.f, 0.f, 0.f};
#pragma unroll
    for (int j = 0; j < 8; j++)
#pragma unroll
      for (int r = 0; r < 4; r++) {
        float e = __expf(S[j][r] * scl);
        psum[r] += e;
        B2[par ^ 1][w * (16 * 136) + (q * 4 + r) * 136 + j * 16 + lr] = f2b(e);
      }
#pragma unroll
    for (int r = 0; r < 4; r++) {
#pragma unroll
      for (int o = 1; o < 16; o <<= 1) psum[r] += __shfl_xor(psum[r], o);
      lsum[r] += psum[r];
    }
    bf16x8 Pf[4];  // A-frag: row=lr, k=t4*32+q*8 (same-wave write->read, lgkm-ordered)
#pragma unroll
    for (int t4 = 0; t4 < 4; t4++)
      Pf[t4] = *(const bf16x8*)&B2[par ^ 1][w * (16 * 136) + lr * 136 + t4 * 32 + q * 8];
    __syncthreads();  // all Pf reads done before next DMA overwrites that buffer

    // ---- PV: 4 chunks [128 d x 128 kv]; prefetch next (or next tile's K0) ----
    for (int dc = 0; dc < 4; dc++) {
      if (dc < 3)        { STAGE_V(kv, dc + 1, par ^ 1); }
      else if (kv < 15)  { STAGE_K(kv + 1, 0, par ^ 1); }
#pragma unroll
      for (int t4 = 0; t4 < 4; t4++)
#pragma unroll
        for (int j = 0; j < 8; j++) {
          int row = j * 16 + lr;
          bf16x8 Vf = *(const bf16x8*)&B2[par][row * 128 + (((t4 * 4 + q) ^ lr) * 8)];
          O[dc * 8 + j] = __builtin_amdgcn_mfma_f32_16x16x32_bf16(Pf[t4], Vf, O[dc * 8 + j], 0, 0, 0);
        }
      __syncthreads();
      par ^= 1;
    }
  }

  // ---- epilogue: bf16 partial-O stores (no atomics) ----
  u16* op = attp + (long)half * 16384 * 512;
#pragma unroll
  for (int i = 0; i < 32; i++) {
    int col = (i >> 3) * 128 + (i & 7) * 16 + lr;
#pragma unroll
    for (int r = 0; r < 4; r++)
      op[(rowbase + w * 16 + q * 4 + r) * 512 + col] = f2b(O[i][r]);
  }
  if (lr == 0)
#pragma unroll
    for (int r = 0; r < 4; r++)
      lbp[(long)half * 16384 + rowbase + w * 16 + q * 4 + r] = lsum[r];
}

// ---------------- support kernels ----------------
template <typename TS>
__global__ __launch_bounds__(1024)
void transpose_b(const TS* __restrict__ src, u16* __restrict__ dst,
                 int R, int Cc, int src_ld, long sbs, long dbs) {
  __shared__ u16 tile[32][33];
  int r = blockIdx.y * 32 + threadIdx.y;
  int c = blockIdx.x * 32 + threadIdx.x;
  tile[threadIdx.y][threadIdx.x] = to_b(src[(long)blockIdx.z * sbs + (long)r * src_ld + c]);
  __syncthreads();
  int rr = blockIdx.x * 32 + threadIdx.y;
  int cc = blockIdx.y * 32 + threadIdx.x;
  dst[(long)blockIdx.z * dbs + (long)rr * R + cc] = tile[threadIdx.x][threadIdx.y];
}

__global__ __launch_bounds__(256)
void f32_to_bf16(const float* __restrict__ s, u16* __restrict__ d) {
  long i = ((long)blockIdx.x * 256 + threadIdx.x) * 8;
  float4 a0 = *(const float4*)(s + i);
  float4 a1 = *(const float4*)(s + i + 4);
  u16 tmp[8] = {f2b(a0.x), f2b(a0.y), f2b(a0.z), f2b(a0.w),
                f2b(a1.x), f2b(a1.y), f2b(a1.z), f2b(a1.w)};
  *(uint4*)(d + i) = *(uint4*)tmp;
}

// x1 = LN(x + (p0+p1)/l; g,b) -> bf16. Row 512, 1 row/wave.
__global__ __launch_bounds__(256)
void add_ln_att(const float* __restrict__ X, const u16* __restrict__ attp,
                const float* __restrict__ lbp,
                const float* __restrict__ g, const float* __restrict__ b,
                u16* __restrict__ O) {
  const int row = blockIdx.x * 4 + (threadIdx.x >> 6);
  const int lane = threadIdx.x & 63;
  const size_t base = (size_t)row * 512 + lane * 8;
  const float inv = 1.0f / (lbp[row] + lbp[16384 + row]);
  uint4 p0 = *(const uint4*)(attp + base);
  uint4 p1 = *(const uint4*)(attp + 16384L * 512 + base);
  const u16* s0 = (const u16*)&p0;
  const u16* s1 = (const u16*)&p1;
  float z[8];
  float s1a = 0.f, s2a = 0.f;
#pragma unroll
  for (int i = 0; i < 8; i++) {
    z[i] = X[base + i] + (b2f(s0[i]) + b2f(s1[i])) * inv;
    s1a += z[i]; s2a += z[i] * z[i];
  }
#pragma unroll
  for (int o = 32; o > 0; o >>= 1) { s1a += __shfl_xor(s1a, o); s2a += __shfl_xor(s2a, o); }
  const float mu = s1a * (1.0f / 512.0f);
  const float var = s2a * (1.0f / 512.0f) - mu * mu;
  const float rstd = rsqrtf(var + 1e-5f);
#pragma unroll
  for (int i = 0; i < 8; i++) {
    int c = lane * 8 + i;
    O[base + i] = f2b((z[i] - mu) * rstd * g[c] + b[c]);
  }
}

// out = LN(x1 + p0 + p1 + eb; g,b) -> fp32. Row 512, 1 row/wave.
__global__ __launch_bounds__(256)
void add_ln_ffn(const u16* __restrict__ X, const u16* __restrict__ P0,
                const u16* __restrict__ P1, const float* __restrict__ eb,
                const float* __restrict__ g, const float* __restrict__ b,
                float* __restrict__ O) {
  const int row = blockIdx.x * 4 + (threadIdx.x >> 6);
  const int lane = threadIdx.x & 63;
  const size_t base = (size_t)row * 512 + lane * 8;
  uint4 xv = *(const uint4*)(X + base);
  uint4 a0 = *(const uint4*)(P0 + base);
  uint4 a1 = *(const uint4*)(P1 + base);
  const u16* xs = (const u16*)&xv;
  const u16* s0 = (const u16*)&a0;
  const u16* s1 = (const u16*)&a1;
  float z[8];
  float s1a = 0.f, s2a = 0.f;
#pragma unroll
  for (int i = 0; i < 8; i++) {
    int c = lane * 8 + i;
    z[i] = b2f(xs[i]) + b2f(s0[i]) + b2f(s1[i]) + eb[c];
    s1a += z[i]; s2a += z[i] * z[i];
  }
#pragma unroll
  for (int o = 32; o > 0; o >>= 1) { s1a += __shfl_xor(s1a, o); s2a += __shfl_xor(s2a, o); }
  const float mu = s1a * (1.0f / 512.0f);
  const float var = s2a * (1.0f / 512.0f) - mu * mu;
  const float rstd = rsqrtf(var + 1e-5f);
#pragma unroll
  for (int i = 0; i < 8; i++) {
    int c = lane * 8 + i;
    O[base + i] = (z[i] - mu) * rstd * g[c] + b[c];
  }
}

__global__ __launch_bounds__(256)
void concat3(const float* __restrict__ a, const float* __restrict__ b,
             const float* __restrict__ c, float* __restrict__ o) {
  int i = threadIdx.x + blockIdx.x * 256;
  if (i < 512) o[i] = a[i];
  else if (i < 1024) o[i] = b[i - 512];
  else if (i < 1536) o[i] = c[i - 1024];
}

extern "C" void kernel_launch(void* const* d_in, const int* in_sizes, int n_in,
                              void* d_out, int out_size, void* d_ws, size_t ws_size,
                              hipStream_t stream) {
  const float* x   = (const float*)d_in[0];
  const float* Wq  = (const float*)d_in[1];
  const float* bq  = (const float*)d_in[2];
  const float* Wk  = (const float*)d_in[3];
  const float* bk  = (const float*)d_in[4];
  const float* Wv  = (const float*)d_in[5];
  const float* bv  = (const float*)d_in[6];
  const float* g1  = (const float*)d_in[7];
  const float* b1  = (const float*)d_in[8];
  const float* g2  = (const float*)d_in[9];
  const float* b2  = (const float*)d_in[10];
  const float* W1  = (const float*)d_in[11];
  const float* bf1 = (const float*)d_in[12];
  const float* W2  = (const float*)d_in[13];
  const float* bf2 = (const float*)d_in[14];
  float* out = (float*)d_out;

  char* ws = (char*)d_ws;
  const size_t MB = 1048576;
  u16*   QKV   = (u16*)(ws + 0);          // [16384,1536] bf16, 48 MB
  u16*   Vt    = (u16*)(ws + 48 * MB);    // [4,512,4096] bf16, 16 MB
  u16*   attp  = (u16*)(ws + 64 * MB);    // [2][16384,512] bf16 partials, 32 MB
  u16*   h     = (u16*)(ws + 64 * MB);    // [16384,2048] bf16 (after attp dead)
  float* lbp   = (float*)(ws + 128 * MB); // [2][16384] fp32 partial row sums
  u16*   x1    = (u16*)(ws + 129 * MB);   // [16384,512] bf16, 16 MB
  u16*   ffnp  = (u16*)(ws + 145 * MB);   // [2][16384,512] bf16 partials, 32 MB
  u16*   xb    = (u16*)(ws + 145 * MB);   // bf16(x), 16 MB — dead before ffnp written
  u16*   wqkvt = (u16*)(ws + 177 * MB);   // [1536,512] bf16
  u16*   w1t   = wqkvt + 1536 * 512;      // [2048,512] bf16
  u16*   w2t   = w1t + 2048 * 512;        // [512,2048] bf16
  float* bqkv  = (float*)(w2t + 512 * 2048); // [1536] fp32

  dim3 tb(32, 32);
  f32_to_bf16<<<4096, 256, 0, stream>>>(x, xb);
  transpose_b<float><<<dim3(16, 16, 1), tb, 0, stream>>>(Wq, wqkvt,              512, 512, 512, 0, 0);
  transpose_b<float><<<dim3(16, 16, 1), tb, 0, stream>>>(Wk, wqkvt + 512 * 512,  512, 512, 512, 0, 0);
  transpose_b<float><<<dim3(16, 16, 1), tb, 0, stream>>>(Wv, wqkvt + 1024 * 512, 512, 512, 512, 0, 0);
  transpose_b<float><<<dim3(64, 16, 1), tb, 0, stream>>>(W1, w1t, 512, 2048, 2048, 0, 0);
  transpose_b<float><<<dim3(16, 64, 1), tb, 0, stream>>>(W2, w2t, 2048, 512, 512, 0, 0);
  concat3<<<6, 256, 0, stream>>>(bq, bk, bv, bqkv);

  // Fused QKV projection
  gemm_nt<false, false><<<dim3(12, 128, 1), 256, 0, stream>>>(
      xb, wqkvt, bqkv, QKV, 1536, 512, 1, 512, 512, 1536, 0, 0, 0, 1.0f);

  // V^T per batch
  transpose_b<u16><<<dim3(16, 128, 4), tb, 0, stream>>>(
      QKV + 1024, Vt, 4096, 512, 1536, 4096L * 1536, 512L * 4096);

  const float scl = 0.044194173824159216f;  // 1/sqrt(512)
  // Fused attention: 2 KV halves, double-buffered static-LDS pipeline
  flash_attn<<<dim3(64, 2, 4), 256, 0, stream>>>(QKV, Vt, attp, lbp, scl);

  // x1 = LN(x + (p0+p1)/l)
  add_ln_att<<<4096, 256, 0, stream>>>(x, attp, lbp, g1, b1, x1);
  // h = relu(x1 W1 + bf1)   (h overwrites dead attp region)
  gemm_nt<true, false><<<dim3(16, 128, 1), 256, 0, stream>>>(
      x1, w1t, bf1, h, 2048, 512, 1, 512, 512, 2048, 0, 0, 0, 1.0f);
  // ffnp[z] = h[:, z*1024:(z+1)*1024] W2[z*1024:(z+1)*1024, :] (bf16 partials)
  gemm_nt<false, false><<<dim3(4, 128, 2), 256, 0, stream>>>(
      h, w2t, nullptr, ffnp, 512, 1024, 1, 2048, 2048, 512,
      1024, 1024, 16384L * 512, 1.0f);
  // out = LN(x1 + p0 + p1 + bf2) -> fp32
  add_ln_ffn<<<4096, 256, 0, stream>>>(
      x1, ffnp, ffnp + 16384L * 512, bf2, g2, b2, out);
}